// Round 8
// baseline (13552.821 us; speedup 1.0000x reference)
//
#include <hip/hip_runtime.h>

// LSTM autoencoder v8: v6 (proven 13.2ms) + arrival-order per-wave staging.
// - d-slice partitioning: grp=blkid&7 owns dcols grp*64..+63 (weights stay
//   L2-resident per XCD; R5 verified FETCH 24GB->0.9GB).
// - sample-group barriers (32 members) with agent-scope (sc1) atomics only.
// - NEW: each wave polls the 2 member slots whose h slices it stages and
//   stages them in arrival order (overlap straggler wait with staging);
//   coherent h loads are 64-bit (2 floats per atomic load).
// - c-state in registers; carry wiring per verified v5/v6 semantics.

#define Bsz 128
#define Tsz 128
#define Fsz 128
#define Dsz 512
#define ND  2048
#define NBLK 256
#define NTHR 1024

// ---- ws layout (float offsets) ----
// u32 head: [0,256) fslots | [256,768) group slots: group s at 256+s*64
#define OFF_HT0  1024
#define OFF_HT1  (OFF_HT0 + Dsz*Bsz)
#define OFF_HMT  (OFF_HT1 + Dsz*Bsz)
#define OFF_WEND (OFF_HMT + Dsz*Bsz)
// packed weights (gate-interleaved float4: Wp4[dcol*K + k] = {i,f,g,o})
#define OFF_P_EW0   OFF_WEND
#define OFF_P_EU0   (OFF_P_EW0 + Fsz*ND)
#define OFF_P_WSUM  (OFF_P_EU0 + Dsz*ND)
#define OFF_P_WDECA (OFF_P_WSUM + Dsz*ND)
#define OFF_P_DW0   (OFF_P_WDECA + Dsz*ND)
#define OFF_P_DU0   (OFF_P_DW0 + Fsz*ND)
#define OFF_P_DW1   (OFF_P_DU0 + Dsz*ND)
#define OFF_P_DU1   (OFF_P_DW1 + Dsz*ND)
#define OFF_P_BF    (OFF_P_DU1 + Dsz*ND)
#define OFF_P_DWT   (OFF_P_BF + ND)
#define WS_PACKED_FLOATS (OFF_P_DWT + Dsz*Fsz)
// fallback: folded matrices only
#define OFF_F_WSUM  OFF_WEND
#define OFF_F_WDECA (OFF_F_WSUM + Dsz*ND)
#define OFF_F_BF    (OFF_F_WDECA + Dsz*ND)
#define OFF_F_DWT   (OFF_F_BF + ND)
#define WS_FALLBACK_FLOATS (OFF_F_DWT + Dsz*Fsz)

__device__ __forceinline__ float sigf(float x) {
    return 1.0f / (1.0f + __expf(-x));
}

// agent-scope (sc1/LLC) primitives — documented-correct under any placement
__device__ __forceinline__ float ld_coh(const float* p) {
    return __hip_atomic_load((float*)p, __ATOMIC_RELAXED, __HIP_MEMORY_SCOPE_AGENT);
}
__device__ __forceinline__ void st_coh(float* p, float v) {
    __hip_atomic_store(p, v, __ATOMIC_RELAXED, __HIP_MEMORY_SCOPE_AGENT);
}
__device__ __forceinline__ unsigned ldu_coh(const unsigned* p) {
    return __hip_atomic_load((unsigned*)p, __ATOMIC_RELAXED, __HIP_MEMORY_SCOPE_AGENT);
}
__device__ __forceinline__ void ld2_coh(const float* p, float& a, float& b) {
    unsigned long long u = __hip_atomic_load((const unsigned long long*)p,
                                             __ATOMIC_RELAXED, __HIP_MEMORY_SCOPE_AGENT);
    union { unsigned long long u; float f[2]; } cv; cv.u = u;
    a = cv.f[0]; b = cv.f[1];
}

// ---- arrive: release own slot after block-wide drain ----
__device__ __forceinline__ void arrive(unsigned* slot, unsigned ep) {
    __syncthreads();   // drains vmcnt: all coherent h stores acked (LLC)
    if (threadIdx.x == 0)
        __hip_atomic_store(slot, ep, __ATOMIC_RELEASE, __HIP_MEMORY_SCOPE_AGENT);
}

// ---- arrival-order wait+stage: wave v polls members 2v,2v+1; stages each
// slice as soon as its producer arrives. HTsrc[dcol*Bsz + b] -> XL[b*xstr+off+dcol].
__device__ __forceinline__ void wait_stage(float* XL, int xstr, int dstoff,
                                           const float* HTsrc, int row0,
                                           unsigned* gsl, unsigned ep) {
    const int wv = threadIdx.x >> 6;
    const int lane = threadIdx.x & 63;
    #pragma unroll
    for (int q = 0; q < 2; ++q) {
        const int js = wv * 2 + q;
        for (;;) {
            unsigned v = ldu_coh(&gsl[js]);
            if (__all(v >= ep)) break;
            __builtin_amdgcn_s_sleep(1);
        }
        // slice js: dcols (js&7)*64 + (js>>3)*16 + [0,16), 16 samples
        const int dd = ((js & 7) << 6) + ((js >> 3) << 4) + (lane >> 2);
        const int bq = (lane & 3) << 2;
        const float* p = HTsrc + (size_t)dd * Bsz + row0 + bq;
        float f0, f1, f2, f3;
        ld2_coh(p, f0, f1);
        ld2_coh(p + 2, f2, f3);
        float* xb = XL + dstoff + dd;
        xb[(bq + 0) * xstr] = f0;
        xb[(bq + 1) * xstr] = f1;
        xb[(bq + 2) * xstr] = f2;
        xb[(bq + 3) * xstr] = f3;
    }
    __syncthreads();
}

// full-grid barrier (P0 only; fences flush packed weights)
__device__ __forceinline__ void gbar_all(unsigned* slots, int blkid, unsigned ep) {
    __syncthreads();
    if (threadIdx.x == 0) {
        __threadfence();
        __hip_atomic_store(&slots[blkid], ep, __ATOMIC_RELEASE,
                           __HIP_MEMORY_SCOPE_AGENT);
    }
    if (threadIdx.x < 64) {
        for (;;) {
            unsigned mn = ~0u;
            #pragma unroll
            for (int q = 0; q < 4; ++q)
                mn = min(mn, ldu_coh(&slots[threadIdx.x * 4 + q]));
            if (__all(mn >= ep)) break;
            __builtin_amdgcn_s_sleep(1);
        }
        if (threadIdx.x == 0) __threadfence();
    }
    __syncthreads();
}

// ---- static-input staging ----
__device__ __forceinline__ void stage_vec(float* XL, int xstr, int dstoff,
        const float* src, int row0, int ld, int klen, int c4shift) {
    const int q = klen >> 2;
    const int n4 = q * 16;
    for (int i = threadIdx.x; i < n4; i += NTHR) {
        const int row = i >> c4shift;
        const int c4 = i & (q - 1);
        float4 v = *(const float4*)(src + (size_t)(row0 + row) * ld + (c4 << 2));
        *(float4*)(XL + row * xstr + dstoff + (c4 << 2)) = v;
    }
}

// ---- gate accumulation ----
__device__ __forceinline__ void acc_seg(float4& z, const float* xp,
                                        const float4* wp, int ksub) {
    #pragma unroll 4
    for (int j = 0; j < ksub; j += 4) {
        float4 x4 = *(const float4*)(xp + j);
        float4 w0 = wp[j], w1 = wp[j + 1], w2 = wp[j + 2], w3 = wp[j + 3];
        z.x += x4.x*w0.x + x4.y*w1.x + x4.z*w2.x + x4.w*w3.x;
        z.y += x4.x*w0.y + x4.y*w1.y + x4.z*w2.y + x4.w*w3.y;
        z.z += x4.x*w0.z + x4.y*w1.z + x4.z*w2.z + x4.w*w3.z;
        z.w += x4.x*w0.w + x4.y*w1.w + x4.z*w2.w + x4.w*w3.w;
    }
}
__device__ __forceinline__ void acc_segS(float4& z, const float* xp,
                                         const float* W, int kbase, int ksub, int dcol) {
    for (int j = 0; j < ksub; ++j) {
        const float x = xp[j];
        const float* wr = W + (size_t)(kbase + j) * ND + dcol;
        z.x += x * wr[0];
        z.y += x * wr[Dsz];
        z.z += x * wr[2 * Dsz];
        z.w += x * wr[3 * Dsz];
    }
}
__device__ __forceinline__ void reduce4(float4& z) {
    z.x += __shfl_xor(z.x, 16); z.x += __shfl_xor(z.x, 32);
    z.y += __shfl_xor(z.y, 16); z.y += __shfl_xor(z.y, 32);
    z.z += __shfl_xor(z.z, 16); z.z += __shfl_xor(z.z, 32);
    z.w += __shfl_xor(z.w, 16); z.w += __shfl_xor(z.w, 32);
}
__device__ __forceinline__ float lstm_fin(float4 z, const float* bias, int dcol,
                                          float cprev, float& c2out) {
    float gi = sigf(z.x + bias[dcol]);
    float gf = sigf(z.y + bias[Dsz + dcol]);
    float gg = fmaxf(z.z + bias[2 * Dsz + dcol], 0.f);
    float go = sigf(z.w + bias[3 * Dsz + dcol]);
    float c2 = gf * cprev + gi * gg;
    c2out = c2;
    return go * fmaxf(c2, 0.f);
}
// fused dense-row partial: h(@XL cols[0,512)) @ dwT[f][k]
__device__ __forceinline__ void out_part(const float* XL, int xstr, float* ORED,
                                         int b, int kc, int w, int fcol,
                                         const float* dwT) {
    const int q = w >> 2;
    const float* xp = XL + b * xstr + q * 128 + kc * 32;
    const float* wt = dwT + (size_t)fcol * Dsz + q * 128 + kc * 32;
    float acc = 0.f;
    #pragma unroll
    for (int j = 0; j < 32; j += 4) {
        float4 x4 = *(const float4*)(xp + j);
        float4 w4 = *(const float4*)(wt + j);
        acc += x4.x * w4.x + x4.y * w4.y + x4.z * w4.z + x4.w * w4.w;
    }
    acc += __shfl_xor(acc, 16); acc += __shfl_xor(acc, 32);
    if ((threadIdx.x & 63) < 16) ORED[b * 16 + (w & 3) * 4 + q] = acc;
}

// ---- P0 packing ----
__device__ void pack_gate(float* dst, const float* src, int K, int kshift, int gid) {
    const int total = K * Dsz;
    for (int u = gid; u < total; u += NBLK * NTHR) {
        const int dd = u >> kshift;
        const int k = u & (K - 1);
        const float* sp = src + (size_t)k * ND + dd;
        ((float4*)dst)[u] = make_float4(sp[0], sp[Dsz], sp[2 * Dsz], sp[3 * Dsz]);
    }
}
__device__ void pack_wsum(float* dst, const float* a, const float* bsrc, int gid) {
    for (int u = gid; u < Dsz * Dsz; u += NBLK * NTHR) {
        const int dd = u >> 9, k = u & 511;
        const float* pa = a + (size_t)k * ND + dd;
        const float* pb = bsrc + (size_t)k * ND + dd;
        ((float4*)dst)[u] = make_float4(pa[0] + pb[0], pa[Dsz] + pb[Dsz],
                                        pa[2*Dsz] + pb[2*Dsz], pa[3*Dsz] + pb[3*Dsz]);
    }
}
__device__ void pack_wdeca_p(float* dst, const float* dU0, const float* dW0,
                             const float* dw, int gid) {
    for (int u = gid; u < Dsz * Dsz; u += NBLK * NTHR) {
        const int dd = u >> 9, k = u & 511;
        const float* pu = dU0 + (size_t)k * ND + dd;
        float a0 = pu[0], a1 = pu[Dsz], a2 = pu[2*Dsz], a3 = pu[3*Dsz];
        const float* dwr = dw + k * Fsz;
        for (int j = 0; j < Fsz; ++j) {
            const float wv = dwr[j];
            const float* dr = dW0 + (size_t)j * ND + dd;
            a0 += wv * dr[0]; a1 += wv * dr[Dsz];
            a2 += wv * dr[2*Dsz]; a3 += wv * dr[3*Dsz];
        }
        ((float4*)dst)[u] = make_float4(a0, a1, a2, a3);
    }
}

template<bool PACKED>
__global__ void __launch_bounds__(NTHR, 1)
lstm_ae_kernel(const float* enc_in, const float* dec_in,
               const float* eW0, const float* eU0, const float* eb0,
               const float* eW1, const float* eU1, const float* eb1,
               const float* dW0, const float* dU0, const float* db0,
               const float* dW1, const float* dU1, const float* db1,
               const float* dw, const float* db_, float* out, float* ws)
{
    __shared__ float XL[16 * 1028];
    __shared__ float ORED[256];

    unsigned* fslots = (unsigned*)ws;
    float* HT[2] = { ws + OFF_HT0, ws + OFF_HT1 };
    float* HMT = ws + OFF_HMT;

    const int blkid = blockIdx.x;
    const int grp  = blkid & 7;       // XCD / dcol-slice owner
    const int mem  = blkid >> 3;
    const int sgrp = mem & 7;         // sample group (barrier domain)
    const int dslc = mem >> 3;
    const int gm   = dslc * 8 + grp;  // member id within group (0..31)
    unsigned* gsl = (unsigned*)ws + 256 + sgrp * 64;

    const int tid  = threadIdx.x;
    const int w    = tid >> 6;
    const int lane = tid & 63;
    const int b    = lane & 15;
    const int kc   = lane >> 4;
    const int dcol = grp * 64 + dslc * 16 + w;
    const int bgl  = sgrp * 16 + b;
    const int row0 = sgrp * 16;
    const int fcol = grp * 16 + dslc * 4 + (w & 3);
    const int gid  = blkid * NTHR + tid;

    const float *pEW0, *pEU0, *pWSUM, *pWDECA, *pDW0, *pDU0, *pDW1, *pDU1, *pBF, *pDWT;

    // ---- P0 ----
    if (PACKED) {
        pack_gate(ws + OFF_P_EW0, eW0, Fsz, 7, gid);
        pack_gate(ws + OFF_P_EU0, eU0, Dsz, 9, gid);
        pack_wsum(ws + OFF_P_WSUM, eW1, eU1, gid);
        pack_wdeca_p(ws + OFF_P_WDECA, dU0, dW0, dw, gid);
        pack_gate(ws + OFF_P_DW0, dW0, Fsz, 7, gid);
        pack_gate(ws + OFF_P_DU0, dU0, Dsz, 9, gid);
        pack_gate(ws + OFF_P_DW1, dW1, Dsz, 9, gid);
        pack_gate(ws + OFF_P_DU1, dU1, Dsz, 9, gid);
        if (gid < ND) {
            float acc = db0[gid];
            for (int j = 0; j < Fsz; ++j) acc += db_[j] * dW0[(size_t)j * ND + gid];
            (ws + OFF_P_BF)[gid] = acc;
        }
        if (gid < Dsz * Fsz) {
            const int f = gid >> 9, k = gid & 511;
            (ws + OFF_P_DWT)[(size_t)f * Dsz + k] = dw[(size_t)k * Fsz + f];
        }
        pEW0 = ws + OFF_P_EW0; pEU0 = ws + OFF_P_EU0; pWSUM = ws + OFF_P_WSUM;
        pWDECA = ws + OFF_P_WDECA; pDW0 = ws + OFF_P_DW0; pDU0 = ws + OFF_P_DU0;
        pDW1 = ws + OFF_P_DW1; pDU1 = ws + OFF_P_DU1; pBF = ws + OFF_P_BF;
        pDWT = ws + OFF_P_DWT;
    } else {
        pack_wsum(ws + OFF_F_WSUM, eW1, eU1, gid);
        pack_wdeca_p(ws + OFF_F_WDECA, dU0, dW0, dw, gid);
        if (gid < ND) {
            float acc = db0[gid];
            for (int j = 0; j < Fsz; ++j) acc += db_[j] * dW0[(size_t)j * ND + gid];
            (ws + OFF_F_BF)[gid] = acc;
        }
        if (gid < Dsz * Fsz) {
            const int f = gid >> 9, k = gid & 511;
            (ws + OFF_F_DWT)[(size_t)f * Dsz + k] = dw[(size_t)k * Fsz + f];
        }
        pEW0 = eW0; pEU0 = eU0; pWSUM = ws + OFF_F_WSUM;
        pWDECA = ws + OFF_F_WDECA; pDW0 = dW0; pDU0 = dU0;
        pDW1 = dW1; pDU1 = dU1; pBF = ws + OFF_F_BF;
        pDWT = ws + OFF_F_DWT;
    }
    gbar_all(fslots, blkid, 1);

    unsigned ep = 0;       // completed-phase epoch
    int cur = 0;
    float c_car = 0.f;     // scan carry (lanes<16 valid)

    // ---- encoder ----
    for (int t = 0; t < Tsz; ++t) {
        // L0: prestage x_t + x-partial BEFORE waiting for h_{t-1}
        stage_vec(XL, 644, 0, enc_in + (size_t)t * Fsz, row0, Tsz * Fsz, 128, 5);
        __syncthreads();
        float4 z = make_float4(0.f, 0.f, 0.f, 0.f);
        if (PACKED) acc_seg(z, XL + b * 644 + kc * 32,
                            (const float4*)pEW0 + (size_t)dcol * 128 + kc * 32, 32);
        else        acc_segS(z, XL + b * 644 + kc * 32, pEW0, kc * 32, 32, dcol);
        wait_stage(XL, 644, 128, HT[cur], row0, gsl, ep);
        if (PACKED) acc_seg(z, XL + b * 644 + 128 + kc * 128,
                            (const float4*)pEU0 + (size_t)dcol * 512 + kc * 128, 128);
        else        acc_segS(z, XL + b * 644 + 128 + kc * 128, pEU0, kc * 128, 128, dcol);
        reduce4(z);
        float c1 = 0.f;
        if (lane < 16) {
            float h2 = lstm_fin(z, eb0, dcol, c_car, c1);
            st_coh(&HMT[(size_t)dcol * Bsz + bgl], h2);
        }
        arrive(&gsl[gm], ++ep);
        // L1: h1@(eW1+eU1); cprev = c1 (this step's L0 c)
        wait_stage(XL, 516, 0, HMT, row0, gsl, ep);
        z = make_float4(0.f, 0.f, 0.f, 0.f);
        acc_seg(z, XL + b * 516 + kc * 128,
                (const float4*)pWSUM + (size_t)dcol * 512 + kc * 128, 128);
        reduce4(z);
        if (lane < 16) {
            float c2;
            float h2 = lstm_fin(z, eb1, dcol, c1, c2);
            c_car = c2;
            st_coh(&HT[cur ^ 1][(size_t)dcol * Bsz + bgl], h2);
        }
        arrive(&gsl[gm], ++ep);
        cur ^= 1;
    }

    // ---- decoder t=0 (both layers consume OLD carry; L0 c discarded) ----
    stage_vec(XL, 644, 0, dec_in, row0, Tsz * Fsz, 128, 5);
    __syncthreads();
    {
        float4 z = make_float4(0.f, 0.f, 0.f, 0.f);
        if (PACKED) acc_seg(z, XL + b * 644 + kc * 32,
                            (const float4*)pDW0 + (size_t)dcol * 128 + kc * 32, 32);
        else        acc_segS(z, XL + b * 644 + kc * 32, pDW0, kc * 32, 32, dcol);
        wait_stage(XL, 644, 128, HT[cur], row0, gsl, ep);
        if (PACKED) acc_seg(z, XL + b * 644 + 128 + kc * 128,
                            (const float4*)pDU0 + (size_t)dcol * 512 + kc * 128, 128);
        else        acc_segS(z, XL + b * 644 + 128 + kc * 128, pDU0, kc * 128, 128, dcol);
        reduce4(z);
        if (lane < 16) {
            float cd;
            float h2 = lstm_fin(z, db0, dcol, c_car, cd);
            st_coh(&HMT[(size_t)dcol * Bsz + bgl], h2);
        }
        arrive(&gsl[gm], ++ep);
    }
    // t=0 L1: stage h(old)->[0,512) and hA->[512,1024)
    wait_stage(XL, 1028, 0, HT[cur], row0, gsl, ep);  // h(old) ready since ep-1
    wait_stage(XL, 1028, 512, HMT, row0, gsl, ep);
    {
        float4 z = make_float4(0.f, 0.f, 0.f, 0.f);
        if (PACKED) {
            acc_seg(z, XL + b * 1028 + kc * 128,
                    (const float4*)pDU1 + (size_t)dcol * 512 + kc * 128, 128);
            acc_seg(z, XL + b * 1028 + 512 + kc * 128,
                    (const float4*)pDW1 + (size_t)dcol * 512 + kc * 128, 128);
        } else {
            acc_segS(z, XL + b * 1028 + kc * 128, pDU1, kc * 128, 128, dcol);
            acc_segS(z, XL + b * 1028 + 512 + kc * 128, pDW1, kc * 128, 128, dcol);
        }
        reduce4(z);
        if (lane < 16) {
            float c2;
            float h2 = lstm_fin(z, db1, dcol, c_car, c2);
            c_car = c2;
            st_coh(&HT[cur ^ 1][(size_t)dcol * Bsz + bgl], h2);
        }
    }
    arrive(&gsl[gm], ++ep);
    cur ^= 1;

    // ---- decoder t=1..127 ----
    for (int t = 1; t < Tsz; ++t) {
        const int tt = Tsz - t;
        // L0 folded: h@WdecA + bfold ; fused out_{t-1} partials; h stays in LDS
        wait_stage(XL, 1028, 0, HT[cur], row0, gsl, ep);
        {
            float4 z = make_float4(0.f, 0.f, 0.f, 0.f);
            acc_seg(z, XL + b * 1028 + kc * 128,
                    (const float4*)pWDECA + (size_t)dcol * 512 + kc * 128, 128);
            reduce4(z);
            out_part(XL, 1028, ORED, b, kc, w, fcol, pDWT);
            if (lane < 16) {
                float cd;
                float h2 = lstm_fin(z, pBF, dcol, c_car, cd);
                st_coh(&HMT[(size_t)dcol * Bsz + bgl], h2);
            }
        }
        arrive(&gsl[gm], ++ep);
        if (tid < 64) {   // out row emit off the critical path
            const int bb = tid >> 2, ff = tid & 3;
            const int fc = grp * 16 + dslc * 4 + ff;
            const float* r = ORED + bb * 16 + ff * 4;
            float sm = r[0] + r[1] + r[2] + r[3] + db_[fc];
            out[((size_t)(row0 + bb) * Tsz + tt) * Fsz + fc] = sm;
        }
        // L1: hA@dW1 + h@dU1 ; h reused from LDS cols [0,512)
        wait_stage(XL, 1028, 512, HMT, row0, gsl, ep);
        {
            float4 z = make_float4(0.f, 0.f, 0.f, 0.f);
            if (PACKED) {
                acc_seg(z, XL + b * 1028 + kc * 128,
                        (const float4*)pDU1 + (size_t)dcol * 512 + kc * 128, 128);
                acc_seg(z, XL + b * 1028 + 512 + kc * 128,
                        (const float4*)pDW1 + (size_t)dcol * 512 + kc * 128, 128);
            } else {
                acc_segS(z, XL + b * 1028 + kc * 128, pDU1, kc * 128, 128, dcol);
                acc_segS(z, XL + b * 1028 + 512 + kc * 128, pDW1, kc * 128, 128, dcol);
            }
            reduce4(z);
            if (lane < 16) {
                float c2;
                float h2 = lstm_fin(z, db1, dcol, c_car, c2);
                c_car = c2;
                st_coh(&HT[cur ^ 1][(size_t)dcol * Bsz + bgl], h2);
            }
        }
        arrive(&gsl[gm], ++ep);
        cur ^= 1;
    }

    // ---- final: out_127 -> row 0 ----
    wait_stage(XL, 516, 0, HT[cur], row0, gsl, ep);
    out_part(XL, 516, ORED, b, kc, w, fcol, pDWT);
    __syncthreads();
    if (tid < 64) {
        const int bb = tid >> 2, ff = tid & 3;
        const int fc = grp * 16 + dslc * 4 + ff;
        const float* r = ORED + bb * 16 + ff * 4;
        float sm = r[0] + r[1] + r[2] + r[3] + db_[fc];
        out[((size_t)(row0 + bb) * Tsz + 0) * Fsz + fc] = sm;
    }
}

extern "C" void kernel_launch(void* const* d_in, const int* in_sizes, int n_in,
                              void* d_out, int out_size, void* d_ws, size_t ws_size,
                              hipStream_t stream) {
    (void)in_sizes; (void)n_in; (void)out_size;
    const float* enc_in = (const float*)d_in[0];
    const float* dec_in = (const float*)d_in[1];
    const float* eW0 = (const float*)d_in[2];
    const float* eU0 = (const float*)d_in[3];
    const float* eb0 = (const float*)d_in[4];
    const float* eW1 = (const float*)d_in[5];
    const float* eU1 = (const float*)d_in[6];
    const float* eb1 = (const float*)d_in[7];
    const float* dW0 = (const float*)d_in[8];
    const float* dU0 = (const float*)d_in[9];
    const float* db0 = (const float*)d_in[10];
    const float* dW1 = (const float*)d_in[11];
    const float* dU1 = (const float*)d_in[12];
    const float* db1 = (const float*)d_in[13];
    const float* dw  = (const float*)d_in[14];
    const float* db_ = (const float*)d_in[15];
    float* out = (float*)d_out;
    float* ws = (float*)d_ws;

    // zero: barrier slots + HT0 (initial h = 0)
    hipMemsetAsync(d_ws, 0, (size_t)(OFF_HT0 + Dsz * Bsz) * sizeof(float), stream);

    const bool packed = ws_size >= (size_t)WS_PACKED_FLOATS * sizeof(float);
    if (packed)
        lstm_ae_kernel<true><<<NBLK, NTHR, 0, stream>>>(
            enc_in, dec_in, eW0, eU0, eb0, eW1, eU1, eb1,
            dW0, dU0, db0, dW1, dU1, db1, dw, db_, out, ws);
    else
        lstm_ae_kernel<false><<<NBLK, NTHR, 0, stream>>>(
            enc_in, dec_in, eW0, eU0, eb0, eW1, eU1, eb1,
            dW0, dU0, db0, dW1, dU1, db1, dw, db_, out, ws);
}